// Round 1
// baseline (91.350 us; speedup 1.0000x reference)
//
#include <hip/hip_runtime.h>
#include <math.h>

// Problem constants (fixed by setup_inputs): B=8, L=4096, D=64, M=qkv_size=64, masked=1.
#define BB 8
#define LL 4096
#define DD 64
#define MM 64
#define SS 64            // chunk size along L
#define NCHUNK 64        // LL / SS
#define STATE 4160       // MM*DD + MM  (KV chunk sum + N chunk sum)

// XOR swizzle on column index (multiple of 4 -> float4-aligned blocks preserved).
#define SW(r) ((r) & 28)

// ---------------- K1: per-timestep scales ----------------
// scale[t] = exp(-0.5 * sqrt(sum_{b,d} X[b,t,d]^2)); ws[0..L) = scaleQ, ws[L..2L) = scaleK.
__global__ __launch_bounds__(256) void k_scales(const float* __restrict__ Q,
                                                const float* __restrict__ K,
                                                float* __restrict__ ws) {
  const int t = blockIdx.x * 4 + (threadIdx.x >> 6);
  const int lane = threadIdx.x & 63;
  const int b = lane >> 3;
  const int d0 = (lane & 7) * 8;
  const size_t base = (size_t)b * (LL * DD) + (size_t)t * DD + d0;
  float sq = 0.f, sk = 0.f;
#pragma unroll
  for (int k = 0; k < 8; ++k) {
    const float q = Q[base + k]; sq += q * q;
    const float kk = K[base + k]; sk += kk * kk;
  }
#pragma unroll
  for (int off = 32; off; off >>= 1) {
    sq += __shfl_xor(sq, off);
    sk += __shfl_xor(sk, off);
  }
  if (lane == 0) {
    ws[t]      = expf(-0.5f * sqrtf(sq));
    ws[LL + t] = expf(-0.5f * sqrtf(sk));
  }
}

// ---------------- shared helpers ----------------
__device__ __forceinline__ void stage_tile(float* __restrict__ dst,
                                           const float* __restrict__ src, int tid) {
  const int r = tid >> 4;
  const int col = (tid & 15) * 4;
#pragma unroll
  for (int it = 0; it < 4; ++it) {
    const int row = r + it * 16;
    *(float4*)(dst + row * 64 + col) = *(const float4*)(src + row * 64 + col);
  }
}

__device__ __forceinline__ void stage_proj_swz(float* __restrict__ dst,
                                               const float* __restrict__ src, int tid) {
  const int r = tid >> 4;
  const int col = (tid & 15) * 4;
#pragma unroll
  for (int it = 0; it < 4; ++it) {
    const int m = r + it * 16;
    *(float4*)(dst + m * 64 + (col ^ SW(m))) = *(const float4*)(src + m * 64 + col);
  }
}

// PHI[t][m] = exp( X[t,:] . proj[m,:] ) * scaleBase[t] * (1/sqrt(M));  stored col-swizzled by row.
__device__ __forceinline__ void compute_phi(const float* __restrict__ Xs,
                                            const float* __restrict__ PRs,
                                            float* __restrict__ PHI,
                                            const float* __restrict__ scaleBase,
                                            int tB, int g2) {
  float acc[4][4] = {};
#pragma unroll
  for (int d4 = 0; d4 < 16; ++d4) {
    float4 xv[4], pv[4];
#pragma unroll
    for (int i = 0; i < 4; ++i) xv[i] = *(const float4*)(Xs + (tB + i) * 64 + d4 * 4);
#pragma unroll
    for (int j = 0; j < 4; ++j) {
      const int m = g2 + j;
      pv[j] = *(const float4*)(PRs + m * 64 + ((d4 * 4) ^ SW(m)));
    }
#pragma unroll
    for (int i = 0; i < 4; ++i)
#pragma unroll
      for (int j = 0; j < 4; ++j)
        acc[i][j] += xv[i].x * pv[j].x + xv[i].y * pv[j].y +
                     xv[i].z * pv[j].z + xv[i].w * pv[j].w;
  }
#pragma unroll
  for (int i = 0; i < 4; ++i) {
    const int t = tB + i;
    const float sc = scaleBase[t] * 0.125f;  // 1/sqrt(64)
    float4 ph;
    ph.x = expf(acc[i][0]) * sc;
    ph.y = expf(acc[i][1]) * sc;
    ph.z = expf(acc[i][2]) * sc;
    ph.w = expf(acc[i][3]) * sc;
    *(float4*)(PHI + t * 64 + (g2 ^ SW(t))) = ph;
  }
}

// ---------------- K2: per-chunk sums: KV_c = phiK^T V (64x64), N_c = colsum(phiK) ----------------
__global__ __launch_bounds__(256) void k_chunk_sums(const float* __restrict__ Kg,
                                                    const float* __restrict__ Vg,
                                                    const float* __restrict__ proj,
                                                    const float* __restrict__ ws,
                                                    float* __restrict__ states) {
  __shared__ float PR[4096];
  __shared__ float X[4096];
  __shared__ float PH[4096];
  const int tid = threadIdx.x;
  const int bc = blockIdx.x;
  const int b = bc >> 6;
  const int c = bc & (NCHUNK - 1);
  const int t0 = c * SS;
  const size_t tileBase = ((size_t)b * LL + t0) * DD;

  stage_proj_swz(PR, proj, tid);
  stage_tile(X, Kg + tileBase, tid);
  __syncthreads();

  const int tB = (tid >> 4) * 4;
  const int g2 = (tid & 15) * 4;
  compute_phi(X, PR, PH, ws + LL + t0, tB, g2);
  __syncthreads();

  stage_tile(X, Vg + tileBase, tid);  // V overwrites K
  __syncthreads();

  // thread owns (m rows tB..tB+3) x (d cols g2..g2+3)
  float kv[4][4] = {};
  float ns[4] = {};
#pragma unroll 4
  for (int t = 0; t < 64; ++t) {
    const float4 ph = *(const float4*)(PH + t * 64 + (tB ^ SW(t)));
    const float4 v  = *(const float4*)(X + t * 64 + g2);
    const float p0 = ph.x, p1 = ph.y, p2 = ph.z, p3 = ph.w;
    ns[0] += p0; ns[1] += p1; ns[2] += p2; ns[3] += p3;
    kv[0][0] += p0 * v.x; kv[0][1] += p0 * v.y; kv[0][2] += p0 * v.z; kv[0][3] += p0 * v.w;
    kv[1][0] += p1 * v.x; kv[1][1] += p1 * v.y; kv[1][2] += p1 * v.z; kv[1][3] += p1 * v.w;
    kv[2][0] += p2 * v.x; kv[2][1] += p2 * v.y; kv[2][2] += p2 * v.z; kv[2][3] += p2 * v.w;
    kv[3][0] += p3 * v.x; kv[3][1] += p3 * v.y; kv[3][2] += p3 * v.z; kv[3][3] += p3 * v.w;
  }

  float* st = states + ((size_t)b * NCHUNK + c) * STATE;
#pragma unroll
  for (int i = 0; i < 4; ++i) {
    float4 w; w.x = kv[i][0]; w.y = kv[i][1]; w.z = kv[i][2]; w.w = kv[i][3];
    *(float4*)(st + (tB + i) * 64 + g2) = w;
  }
  if ((tid & 15) == 0) {
#pragma unroll
    for (int i = 0; i < 4; ++i) st[4096 + tB + i] = ns[i];
  }
}

// ---------------- K3: exclusive prefix over chunks (in place) ----------------
__global__ __launch_bounds__(256) void k_prefix(float* __restrict__ states) {
  const int e = blockIdx.x * 256 + threadIdx.x;
  if (e >= BB * STATE) return;
  const int b = e / STATE;
  const int el = e % STATE;
  float* p = states + (size_t)b * NCHUNK * STATE + el;
  float run = 0.f;
#pragma unroll 4
  for (int c = 0; c < NCHUNK; ++c) {
    const float v = p[(size_t)c * STATE];
    p[(size_t)c * STATE] = run;
    run += v;
  }
}

// ---------------- K4: outputs ----------------
__global__ __launch_bounds__(256) void k_out(const float* __restrict__ Qg,
                                             const float* __restrict__ Kg,
                                             const float* __restrict__ Vg,
                                             const float* __restrict__ proj,
                                             const float* __restrict__ ws,
                                             const float* __restrict__ states,
                                             float* __restrict__ out) {
  __shared__ float PR[4096];  // proj (swz) -> KV_prefix
  __shared__ float X[4096];   // Q -> K -> A
  __shared__ float PQ[4096];  // phiQ (swz)
  __shared__ float PK[4096];  // phiK (swz) -> V
  const int tid = threadIdx.x;
  const int bc = blockIdx.x;
  const int b = bc >> 6;
  const int c = bc & (NCHUNK - 1);
  const int t0 = c * SS;
  const size_t tileBase = ((size_t)b * LL + t0) * DD;

  stage_proj_swz(PR, proj, tid);
  stage_tile(X, Qg + tileBase, tid);
  __syncthreads();

  const int tB = (tid >> 4) * 4;
  const int g2 = (tid & 15) * 4;

  compute_phi(X, PR, PQ, ws + t0, tB, g2);          // phiQ
  __syncthreads();

  stage_tile(X, Kg + tileBase, tid);
  __syncthreads();

  compute_phi(X, PR, PK, ws + LL + t0, tB, g2);     // phiK
  __syncthreads();

  // A = tril(phiQ . phiK^T) -> X  (thread: rows tB.., cols g2..)
  {
    float a[4][4] = {};
#pragma unroll
    for (int m4 = 0; m4 < 16; ++m4) {
      float4 pq[4], pk[4];
#pragma unroll
      for (int i = 0; i < 4; ++i)
        pq[i] = *(const float4*)(PQ + (tB + i) * 64 + ((m4 * 4) ^ SW(tB + i)));
#pragma unroll
      for (int j = 0; j < 4; ++j)
        pk[j] = *(const float4*)(PK + (g2 + j) * 64 + ((m4 * 4) ^ SW(g2 + j)));
#pragma unroll
      for (int i = 0; i < 4; ++i)
#pragma unroll
        for (int j = 0; j < 4; ++j)
          a[i][j] += pq[i].x * pk[j].x + pq[i].y * pk[j].y +
                     pq[i].z * pk[j].z + pq[i].w * pk[j].w;
    }
#pragma unroll
    for (int i = 0; i < 4; ++i) {
      const int t = tB + i;
      float4 av;
      av.x = (g2 + 0 <= t) ? a[i][0] : 0.f;
      av.y = (g2 + 1 <= t) ? a[i][1] : 0.f;
      av.z = (g2 + 2 <= t) ? a[i][2] : 0.f;
      av.w = (g2 + 3 <= t) ? a[i][3] : 0.f;
      *(float4*)(X + t * 64 + g2) = av;
    }
  }
  __syncthreads();

  const float* st = states + ((size_t)b * NCHUNK + c) * STATE;
  stage_tile(PR, st, tid);               // KV_prefix
  stage_tile(PK, Vg + tileBase, tid);    // V
  __syncthreads();

  // out rows tB.., cols g2..
  {
    float o[4][4] = {};
    float rs[4] = {};
#pragma unroll 4
    for (int j = 0; j < 64; ++j) {
      const float4 v = *(const float4*)(PK + j * 64 + g2);
#pragma unroll
      for (int i = 0; i < 4; ++i) {
        const float a = X[(tB + i) * 64 + j];
        rs[i] += a;
        o[i][0] += a * v.x; o[i][1] += a * v.y; o[i][2] += a * v.z; o[i][3] += a * v.w;
      }
    }
    const float* Np = st + 4096;
#pragma unroll 4
    for (int m = 0; m < 64; ++m) {
      const float np = Np[m];
      const float4 kv = *(const float4*)(PR + m * 64 + g2);
#pragma unroll
      for (int i = 0; i < 4; ++i) {
        const float pq = PQ[(tB + i) * 64 + (m ^ SW(tB + i))];
        rs[i] += pq * np;
        o[i][0] += pq * kv.x; o[i][1] += pq * kv.y; o[i][2] += pq * kv.z; o[i][3] += pq * kv.w;
      }
    }
    float* ob = out + tileBase;
#pragma unroll
    for (int i = 0; i < 4; ++i) {
      const float r = rs[i];
      const float inv = 1.f / (r + copysignf(1e-6f, r));
      float4 w;
      w.x = o[i][0] * inv; w.y = o[i][1] * inv; w.z = o[i][2] * inv; w.w = o[i][3] * inv;
      *(float4*)(ob + (tB + i) * 64 + g2) = w;
    }
  }
}

extern "C" void kernel_launch(void* const* d_in, const int* in_sizes, int n_in,
                              void* d_out, int out_size, void* d_ws, size_t ws_size,
                              hipStream_t stream) {
  (void)in_sizes; (void)n_in; (void)out_size; (void)ws_size;
  const float* Q    = (const float*)d_in[0];
  const float* K    = (const float*)d_in[1];
  const float* V    = (const float*)d_in[2];
  const float* proj = (const float*)d_in[4];   // d_in[3] = sent_embed_slice (unused by reference)
  float* out = (float*)d_out;
  float* ws  = (float*)d_ws;                   // [0,L): scaleQ, [L,2L): scaleK, then states
  float* states = ws + 2 * LL;                 // B*NCHUNK*STATE floats (~8.5 MB)

  hipLaunchKernelGGL(k_scales, dim3(LL / 4), dim3(256), 0, stream, Q, K, ws);
  hipLaunchKernelGGL(k_chunk_sums, dim3(BB * NCHUNK), dim3(256), 0, stream, K, V, proj, ws, states);
  hipLaunchKernelGGL(k_prefix, dim3((BB * STATE + 255) / 256), dim3(256), 0, stream, states);
  hipLaunchKernelGGL(k_out, dim3(BB * NCHUNK), dim3(256), 0, stream, Q, K, V, proj, ws, states, out);
}

// Round 3
// 34.617 us; speedup vs baseline: 2.6389x; 2.6389x over previous
//
#include <hip/hip_runtime.h>
#include <math.h>

// B=8, L=4096, D=64, M=64, masked=1 (fixed by setup_inputs)
#define BB 8
#define LL 4096
#define DD 64
#define SS 64
#define NCHUNK 64
#define STATE 4160  // 64x64 KV^T rows (d-major) + 64 N values

typedef __attribute__((ext_vector_type(8))) short s16x8;
typedef __attribute__((ext_vector_type(8))) unsigned short u16x8;
typedef __attribute__((ext_vector_type(4))) float f32x4;

#define MFMA(a, b, c) __builtin_amdgcn_mfma_f32_16x16x32_bf16((a), (b), (c), 0, 0, 0)

static __device__ __forceinline__ unsigned short f2bf(float x) {
  unsigned int u = __builtin_bit_cast(unsigned int, x);
  u += 0x7FFFu + ((u >> 16) & 1u);
  return (unsigned short)(u >> 16);
}
static __device__ __forceinline__ float bf2f(unsigned short h) {
  unsigned int u = ((unsigned int)h) << 16;
  return __builtin_bit_cast(float, u);
}

// Fragment load from an operand tile stored row-major (64 cols of bf16 per row)
// with XOR swizzle: element (r, k) lives at ushort index r*64 + (k ^ ((r&7)<<3)).
// A-frag: row = row0 + (lane&15), k = ks*32 + (lane>>4)*8 + i  (same pattern for B^T).
static __device__ __forceinline__ s16x8 ld_frag(const unsigned short* base, int row0, int ks) {
  const int lane = threadIdx.x & 63;
  const int r = row0 + (lane & 15);
  const int idx = r * 64 + ((ks * 32 + ((lane & 48) >> 1)) ^ ((r & 7) << 3));
  return *(const s16x8*)(base + idx);
}

// Stage a 64x64 f32 global tile into hi/lo bf16 LDS tiles (swizzled).
static __device__ __forceinline__ void stage_hl(unsigned short* __restrict__ Sh,
                                                unsigned short* __restrict__ Sl,
                                                const float* __restrict__ src, int tid) {
#pragma unroll
  for (int it = 0; it < 2; ++it) {
    const int g = tid + it * 256;
    const int row = g >> 3;
    const int c0 = (g & 7) * 8;
    const float4 x0 = *(const float4*)(src + row * 64 + c0);
    const float4 x1 = *(const float4*)(src + row * 64 + c0 + 4);
    const float xs[8] = {x0.x, x0.y, x0.z, x0.w, x1.x, x1.y, x1.z, x1.w};
    u16x8 h, l;
#pragma unroll
    for (int k = 0; k < 8; ++k) {
      const unsigned short hh = f2bf(xs[k]);
      h[k] = hh;
      l[k] = f2bf(xs[k] - bf2f(hh));
    }
    const int idx = row * 64 + (c0 ^ ((row & 7) << 3));
    *(u16x8*)(Sh + idx) = h;
    *(u16x8*)(Sl + idx) = l;
  }
}

// 3-term split-precision logits: acc += Ah*Bh + Ah*Bl + Al*Bh  (wave row-tile w)
static __device__ __forceinline__ void logits3(const unsigned short* Ah_, const unsigned short* Al_,
                                               const unsigned short* Bh_, const unsigned short* Bl_,
                                               int w, f32x4 acc[4]) {
  s16x8 ah[2], al[2];
#pragma unroll
  for (int ks = 0; ks < 2; ++ks) {
    ah[ks] = ld_frag(Ah_, w * 16, ks);
    al[ks] = ld_frag(Al_, w * 16, ks);
  }
#pragma unroll
  for (int ct = 0; ct < 4; ++ct) {
#pragma unroll
    for (int ks = 0; ks < 2; ++ks) {
      const s16x8 bh = ld_frag(Bh_, ct * 16, ks);
      const s16x8 bl = ld_frag(Bl_, ct * 16, ks);
      acc[ct] = MFMA(ah[ks], bh, acc[ct]);
      acc[ct] = MFMA(ah[ks], bl, acc[ct]);
      acc[ct] = MFMA(al[ks], bh, acc[ct]);
    }
  }
}

// phi = exp(logit)*sc; store row-major [t][m] (swizzled).
static __device__ __forceinline__ void phi_store_row(unsigned short* dst, const f32x4* acc,
                                                     const float* sc, int w) {
  const int lane = threadIdx.x & 63;
#pragma unroll
  for (int ri = 0; ri < 4; ++ri) {
    const int t = w * 16 + ((lane & 48) >> 2) + ri;
#pragma unroll
    for (int ct = 0; ct < 4; ++ct) {
      const int m = ct * 16 + (lane & 15);
      dst[t * 64 + (m ^ ((t & 7) << 3))] = f2bf(__expf(acc[ct][ri]) * sc[ri]);
    }
  }
}

// phi stored transposed [m][t] (swizzled) — B-operand layout for KV in chunk sums.
static __device__ __forceinline__ void phi_store_col(unsigned short* dst, const f32x4* acc,
                                                     const float* sc, int w) {
  const int lane = threadIdx.x & 63;
#pragma unroll
  for (int ri = 0; ri < 4; ++ri) {
    const int t = w * 16 + ((lane & 48) >> 2) + ri;
#pragma unroll
    for (int ct = 0; ct < 4; ++ct) {
      const int m = ct * 16 + (lane & 15);
      dst[m * 64 + (t ^ ((m & 7) << 3))] = f2bf(__expf(acc[ct][ri]) * sc[ri]);
    }
  }
}

// Stage one 32-row half of V (f32) into scratch.
static __device__ __forceinline__ void stage_vhalf(float* __restrict__ F, const float* __restrict__ src,
                                                   int tid) {
#pragma unroll
  for (int it = 0; it < 2; ++it) {
    const int g = tid + it * 256;
    const int row = g >> 4;
    const int col = (g & 15) * 4;
    *(float4*)(F + row * 64 + col) = *(const float4*)(src + row * 64 + col);
  }
}

// Transpose scratch half into VT hi/lo bf16 tiles: VT[d][t] (swizzled).
static __device__ __forceinline__ void vtrans_half(unsigned short* __restrict__ Gh,
                                                   unsigned short* __restrict__ Hl,
                                                   const float* __restrict__ F, int tid, int half) {
  const int d = tid & 63;
  const int tb = (tid >> 6) * 8;
  float v[8];
#pragma unroll
  for (int k = 0; k < 8; ++k) v[k] = F[(tb + k) * 64 + d];
  u16x8 hh, ll;
#pragma unroll
  for (int k = 0; k < 8; ++k) {
    const unsigned short h = f2bf(v[k]);
    hh[k] = h;
    ll[k] = f2bf(v[k] - bf2f(h));
  }
  const int idx = d * 64 + ((half * 32 + tb) ^ ((d & 7) << 3));
  *(u16x8*)(Gh + idx) = hh;
  *(u16x8*)(Hl + idx) = ll;
}

// ---------------- K1: per-timestep scales ----------------
__global__ __launch_bounds__(256) void k_scales(const float* __restrict__ Q,
                                                const float* __restrict__ K,
                                                float* __restrict__ ws) {
  const int t = blockIdx.x * 4 + (threadIdx.x >> 6);
  const int lane = threadIdx.x & 63;
  const int b = lane >> 3;
  const int d0 = (lane & 7) * 8;
  const size_t base = (size_t)b * (LL * DD) + (size_t)t * DD + d0;
  float sq = 0.f, sk = 0.f;
#pragma unroll
  for (int k = 0; k < 8; ++k) {
    const float q = Q[base + k]; sq += q * q;
    const float kk = K[base + k]; sk += kk * kk;
  }
#pragma unroll
  for (int off = 32; off; off >>= 1) {
    sq += __shfl_xor(sq, off);
    sk += __shfl_xor(sk, off);
  }
  if (lane == 0) {
    ws[t]      = expf(-0.5f * sqrtf(sq));
    ws[LL + t] = expf(-0.5f * sqrtf(sk));
  }
}

// ---------------- K2: per-chunk sums: KVT[d][m] = (V^T phiK), N[m] ----------------
__global__ __launch_bounds__(256) void k_chunk_sums(const float* __restrict__ Kg,
                                                    const float* __restrict__ Vg,
                                                    const float* __restrict__ proj,
                                                    const float* __restrict__ ws,
                                                    float* __restrict__ states) {
  __shared__ unsigned short A_[4096], B_[4096];  // proj hi/lo
  __shared__ unsigned short C_[4096], D_[4096];  // K hi/lo
  __shared__ unsigned short E_[4096];            // phiK [m][t]
  __shared__ unsigned short G_[4096], H_[4096];  // V^T hi/lo [d][t]
  __shared__ float F_[2048];                     // V f32 half scratch
  const int tid = threadIdx.x;
  const int lane = tid & 63;
  const int w = tid >> 6;
  const int bc = blockIdx.x;
  const int b = bc >> 6;
  const int c = bc & (NCHUNK - 1);
  const int t0 = c * SS;
  const size_t tileBase = ((size_t)b * LL + t0) * DD;
  float* stc = states + ((size_t)b * NCHUNK + c) * (size_t)STATE;

  stage_hl(A_, B_, proj, tid);
  stage_hl(C_, D_, Kg + tileBase, tid);
  stage_vhalf(F_, Vg + tileBase, tid);
  float sck[4];
#pragma unroll
  for (int ri = 0; ri < 4; ++ri) {
    const int trow = w * 16 + ((lane & 48) >> 2) + ri;
    sck[ri] = ws[LL + t0 + trow] * 0.125f;  // * 1/sqrt(64)
  }
  __syncthreads();  // bar0

  {
    f32x4 acc[4] = {};
    logits3(C_, D_, A_, B_, w, acc);
    phi_store_col(E_, acc, sck, w);
  }
  vtrans_half(G_, H_, F_, tid, 0);
  __syncthreads();  // bar1
  stage_vhalf(F_, Vg + tileBase + 32 * 64, tid);
  __syncthreads();  // bar2
  vtrans_half(G_, H_, F_, tid, 1);
  __syncthreads();  // bar3

  // N[m] from quantized phiK (consistency with KV below)
  {
    const int m = tid >> 2, q = tid & 3;
    float s = 0.f;
#pragma unroll
    for (int p = 0; p < 2; ++p) {
      const int tt = q * 16 + p * 8;
      const u16x8 vv = *(const u16x8*)(E_ + m * 64 + (tt ^ ((m & 7) << 3)));
#pragma unroll
      for (int i = 0; i < 8; ++i) s += bf2f(vv[i]);
    }
    s += __shfl_xor(s, 1);
    s += __shfl_xor(s, 2);
    if (q == 0) stc[4096 + m] = s;
  }

  // KVT[d][m] = sum_t VT[d][t] * phiK[t][m]   (V hi/lo split)
  {
    s16x8 avh[2], avl[2];
#pragma unroll
    for (int ks = 0; ks < 2; ++ks) {
      avh[ks] = ld_frag(G_, w * 16, ks);
      avl[ks] = ld_frag(H_, w * 16, ks);
    }
    f32x4 acc[4] = {};
#pragma unroll
    for (int ct = 0; ct < 4; ++ct) {
#pragma unroll
      for (int ks = 0; ks < 2; ++ks) {
        const s16x8 bp = ld_frag(E_, ct * 16, ks);
        acc[ct] = MFMA(avh[ks], bp, acc[ct]);
        acc[ct] = MFMA(avl[ks], bp, acc[ct]);
      }
    }
#pragma unroll
    for (int ri = 0; ri < 4; ++ri) {
      const int d = w * 16 + ((lane & 48) >> 2) + ri;
#pragma unroll
      for (int ct = 0; ct < 4; ++ct) {
        stc[d * 64 + ct * 16 + (lane & 15)] = acc[ct][ri];
      }
    }
  }
}

// ---------------- K3: exclusive prefix over chunks ----------------
__global__ __launch_bounds__(256) void k_prefix(float* __restrict__ states) {
  const int e = blockIdx.x * 256 + threadIdx.x;
  if (e >= BB * STATE) return;
  const int b = e / STATE;
  const int el = e % STATE;
  float* p = states + (size_t)b * NCHUNK * STATE + el;
  float run = 0.f;
#pragma unroll 4
  for (int c = 0; c < NCHUNK; ++c) {
    const float v = p[(size_t)c * STATE];
    p[(size_t)c * STATE] = run;
    run += v;
  }
}

__global__ __launch_bounds__(256) void k_prefix1(const float* __restrict__ states,
                                                 float* __restrict__ tmp) {
  const int e = blockIdx.x * 256 + threadIdx.x;
  if (e >= BB * 8 * STATE) return;
  const int b = e / (8 * STATE);
  const int r = e % (8 * STATE);
  const int g = r / STATE;
  const int el = r % STATE;
  const float* p = states + ((size_t)b * NCHUNK + g * 8) * STATE + el;
  float s = 0.f;
#pragma unroll
  for (int i = 0; i < 8; ++i) s += p[(size_t)i * STATE];
  tmp[((size_t)b * 8 + g) * STATE + el] = s;
}

__global__ __launch_bounds__(256) void k_prefix2(float* __restrict__ states,
                                                 const float* __restrict__ tmp) {
  const int e = blockIdx.x * 256 + threadIdx.x;
  if (e >= BB * 8 * STATE) return;
  const int b = e / (8 * STATE);
  const int r = e % (8 * STATE);
  const int g = r / STATE;
  const int el = r % STATE;
  float run = 0.f;
  for (int g2 = 0; g2 < g; ++g2) run += tmp[((size_t)b * 8 + g2) * STATE + el];
  float* p = states + ((size_t)b * NCHUNK + g * 8) * STATE + el;
#pragma unroll
  for (int i = 0; i < 8; ++i) {
    const float v = p[(size_t)i * STATE];
    p[(size_t)i * STATE] = run;
    run += v;
  }
}

// ---------------- K4: outputs ----------------
__global__ __launch_bounds__(256) void k_out(const float* __restrict__ Qg,
                                             const float* __restrict__ Kg,
                                             const float* __restrict__ Vg,
                                             const float* __restrict__ proj,
                                             const float* __restrict__ ws,
                                             const float* __restrict__ states,
                                             float* __restrict__ out) {
  __shared__ unsigned short A_[4096], B_[4096];  // proj hi/lo -> KV hi/lo
  __shared__ unsigned short C_[4096];            // Qh -> phiQ [t][m]
  __shared__ unsigned short D_[4096];            // Ql -> Kh -> phiK [j][m]
  __shared__ unsigned short E_[4096];            // Kl -> Ah (masked, quantized) [t][j]
  __shared__ unsigned short G_[4096], H_[4096];  // V^T hi/lo [d][t]
  __shared__ float F_[2048];                     // V f32 half scratch
  const int tid = threadIdx.x;
  const int lane = tid & 63;
  const int w = tid >> 6;
  const int bc = blockIdx.x;
  const int b = bc >> 6;
  const int c = bc & (NCHUNK - 1);
  const int t0 = c * SS;
  const size_t tileBase = ((size_t)b * LL + t0) * DD;
  const float* st = states + ((size_t)b * NCHUNK + c) * (size_t)STATE;

  stage_hl(A_, B_, proj, tid);
  stage_hl(C_, D_, Qg + tileBase, tid);
  float scq[4], sck[4];
#pragma unroll
  for (int ri = 0; ri < 4; ++ri) {
    const int trow = w * 16 + ((lane & 48) >> 2) + ri;
    scq[ri] = ws[t0 + trow] * 0.125f;
    sck[ri] = ws[LL + t0 + trow] * 0.125f;
  }
  __syncthreads();  // bar0

  {  // logits Q -> phiQ (in place over Qh: rows are wave-local)
    f32x4 acc[4] = {};
    logits3(C_, D_, A_, B_, w, acc);
    phi_store_row(C_, acc, scq, w);
  }
  __syncthreads();  // bar1 (Ql fully consumed)
  stage_hl(D_, E_, Kg + tileBase, tid);
  __syncthreads();  // bar2
  {  // logits K -> phiK (in place over Kh)
    f32x4 acc[4] = {};
    logits3(D_, E_, A_, B_, w, acc);
    phi_store_row(D_, acc, sck, w);
  }
  __syncthreads();  // bar3 (proj dead, phiK visible)

  stage_hl(A_, B_, st, tid);        // KV prefix hi/lo (rows d of KVT)
  stage_vhalf(F_, Vg + tileBase, tid);
  __syncthreads();  // bar4

  vtrans_half(G_, H_, F_, tid, 0);

  // A = phiQ . phiK^T (per-wave row-tile), masked + quantized; row-sums from quantized A
  float rsI[4];
  {
    s16x8 aq[2];
#pragma unroll
    for (int ks = 0; ks < 2; ++ks) aq[ks] = ld_frag(C_, w * 16, ks);
    f32x4 accA[4] = {};
#pragma unroll
    for (int ct = 0; ct < 4; ++ct) {
#pragma unroll
      for (int ks = 0; ks < 2; ++ks) {
        accA[ct] = MFMA(aq[ks], ld_frag(D_, ct * 16, ks), accA[ct]);
      }
    }
#pragma unroll
    for (int ri = 0; ri < 4; ++ri) {
      const int t = w * 16 + ((lane & 48) >> 2) + ri;
      float part = 0.f;
#pragma unroll
      for (int ct = 0; ct < 4; ++ct) {
        const int j = ct * 16 + (lane & 15);
        const float a = (j <= t) ? accA[ct][ri] : 0.f;
        const unsigned short ah = f2bf(a);
        part += bf2f(ah);
        E_[t * 64 + (j ^ ((t & 7) << 3))] = ah;
      }
#pragma unroll
      for (int off = 1; off < 16; off <<= 1) part += __shfl_xor(part, off);
      rsI[ri] = part;
    }
  }
  __syncthreads();  // bar5
  stage_vhalf(F_, Vg + tileBase + 32 * 64, tid);
  __syncthreads();  // bar6
  vtrans_half(G_, H_, F_, tid, 1);
  __syncthreads();  // bar7

  // acc = A.(VTh+VTl)^T + phiQ.(KVh+KVl);  r = rsI + phiQ.Npref
  {
    s16x8 aA[2], aq[2];
#pragma unroll
    for (int ks = 0; ks < 2; ++ks) {
      aA[ks] = ld_frag(E_, w * 16, ks);
      aq[ks] = ld_frag(C_, w * 16, ks);
    }
    f32x4 acc[4] = {};
#pragma unroll
    for (int ct = 0; ct < 4; ++ct) {
#pragma unroll
      for (int ks = 0; ks < 2; ++ks) {
        acc[ct] = MFMA(aA[ks], ld_frag(G_, ct * 16, ks), acc[ct]);
        acc[ct] = MFMA(aA[ks], ld_frag(H_, ct * 16, ks), acc[ct]);
        acc[ct] = MFMA(aq[ks], ld_frag(A_, ct * 16, ks), acc[ct]);
        acc[ct] = MFMA(aq[ks], ld_frag(B_, ct * 16, ks), acc[ct]);
      }
    }
    // prefix part of denominator: dot(phiQ[t,:], Npref) using the quantized phiQ frags
    float rsp = 0.f;
    const float* Np = st + 4096;
#pragma unroll
    for (int ks = 0; ks < 2; ++ks) {
      const int m0 = ks * 32 + ((lane & 48) >> 1);
      const float4 n0 = *(const float4*)(Np + m0);
      const float4 n1 = *(const float4*)(Np + m0 + 4);
      const float nn[8] = {n0.x, n0.y, n0.z, n0.w, n1.x, n1.y, n1.z, n1.w};
#pragma unroll
      for (int i = 0; i < 8; ++i) rsp += bf2f((unsigned short)aq[ks][i]) * nn[i];
    }
    rsp += __shfl_xor(rsp, 16);
    rsp += __shfl_xor(rsp, 32);
    // rsp now holds r_prefix for row t = w*16 + (lane&15); redistribute to C-row layout
#pragma unroll
    for (int ri = 0; ri < 4; ++ri) {
      const float r = rsI[ri] + __shfl(rsp, ((lane & 48) >> 2) + ri);
      const float inv = 1.f / (r + copysignf(1e-6f, r));
      const int t = w * 16 + ((lane & 48) >> 2) + ri;
#pragma unroll
      for (int ct = 0; ct < 4; ++ct) {
        out[tileBase + t * 64 + ct * 16 + (lane & 15)] = acc[ct][ri] * inv;
      }
    }
  }
}

extern "C" void kernel_launch(void* const* d_in, const int* in_sizes, int n_in,
                              void* d_out, int out_size, void* d_ws, size_t ws_size,
                              hipStream_t stream) {
  (void)in_sizes; (void)n_in; (void)out_size;
  const float* Q    = (const float*)d_in[0];
  const float* K    = (const float*)d_in[1];
  const float* V    = (const float*)d_in[2];
  const float* proj = (const float*)d_in[4];  // d_in[3] = sent_embed_slice (unused)
  float* out = (float*)d_out;
  float* ws  = (float*)d_ws;
  float* states = ws + 2 * LL;
  const size_t statesFloats = (size_t)BB * NCHUNK * STATE;
  float* tmp = states + statesFloats;
  const size_t need2 = (2 * LL + statesFloats + (size_t)BB * 8 * STATE) * sizeof(float);

  hipLaunchKernelGGL(k_scales, dim3(LL / 4), dim3(256), 0, stream, Q, K, ws);
  hipLaunchKernelGGL(k_chunk_sums, dim3(BB * NCHUNK), dim3(256), 0, stream, K, V, proj, ws, states);
  if (ws_size >= need2) {
    hipLaunchKernelGGL(k_prefix1, dim3((BB * 8 * STATE + 255) / 256), dim3(256), 0, stream, states, tmp);
    hipLaunchKernelGGL(k_prefix2, dim3((BB * 8 * STATE + 255) / 256), dim3(256), 0, stream, states, tmp);
  } else {
    hipLaunchKernelGGL(k_prefix, dim3((BB * STATE + 255) / 256), dim3(256), 0, stream, states);
  }
  hipLaunchKernelGGL(k_out, dim3(BB * NCHUNK), dim3(256), 0, stream, Q, K, V, proj, ws, states, out);
}